// Round 2
// baseline (5993.877 us; speedup 1.0000x reference)
//
#include <hip/hip_runtime.h>

#define NN 50000      // nodes
#define NE 800000     // edges
#define NF 128        // node features
#define EF 64         // edge features
#define LSZ 256       // layer size
#define D1 193        // NF+EF+1
#define D2 385        // NF+LSZ+1
#define BN_EPS 1e-5f

// ===========================================================================
// GEMM1 core (templated): Y1[e,j] = sum_k h[e,k] * W1[k,j], bias dropped (BN)
//   h[e,:] = [ x[row[e],0:128], batch[row[e]], edge_attr[e,0:64] ]
// Tile 64 rows x 256 cols, BK=16, 256 threads, 8x8 per thread.
// MODE 0: natural edge order, epilogue accumulates column sum/sumsq (BN stats)
// MODE 1: CSR-permuted order, epilogue = BN affine + ReLU + run-merged
//         scatter-add into aggsum[dest, :]
// ===========================================================================
template <int MODE>
__global__ __launch_bounds__(256) void gemm1_core(
    const float* __restrict__ x, const int* __restrict__ rowi,
    const int* __restrict__ colE, const int* __restrict__ batch,
    const float* __restrict__ edge_attr, const float* __restrict__ W1,
    const int* __restrict__ eidx,        // MODE 1: sorted edge ids
    const float* __restrict__ a1, const float* __restrict__ b1n,  // MODE 1
    float* __restrict__ colsum, float* __restrict__ colsq,        // MODE 0
    float* __restrict__ aggsum)                                    // MODE 1
{
    __shared__ float As[16][68];   // [k][row], padded
    __shared__ float Bs[16][256];  // [k][col]
    __shared__ int   rowE[64];
    __shared__ float bval[64];
    __shared__ int   eS[64];       // edge id per tile row
    __shared__ int   destS[64];    // MODE 1: destination node per row

    const int tid = threadIdx.x;
    const int p0  = blockIdx.x * 64;

    if (tid < 64) {
        int e = (MODE == 1) ? eidx[p0 + tid] : (p0 + tid);
        eS[tid] = e;
        int r = rowi[e];
        rowE[tid] = r;
        bval[tid] = (float)batch[r];
        if (MODE == 1) destS[tid] = colE[e];
    }
    __syncthreads();

    const int tcol = tid & 31;  // *8 -> 256 cols
    const int trow = tid >> 5;  // *8 -> 64 rows

    float acc[8][8];
#pragma unroll
    for (int i = 0; i < 8; i++)
#pragma unroll
        for (int j = 0; j < 8; j++) acc[i][j] = 0.f;

    for (int k0 = 0; k0 < D1; k0 += 16) {
        // A tile (gathered): 64x16, 4 elems/thread
#pragma unroll
        for (int i = 0; i < 4; i++) {
            int lin = tid + i * 256;
            int r = lin >> 4, kk = lin & 15;
            int k = k0 + kk;
            float v;
            if (k < NF)        v = x[(size_t)rowE[r] * NF + k];
            else if (k == NF)  v = bval[r];
            else if (k < D1)   v = edge_attr[(size_t)eS[r] * EF + (k - NF - 1)];
            else               v = 0.f;
            As[kk][r] = v;
        }
        // B tile: 16x256, coalesced
#pragma unroll
        for (int i = 0; i < 16; i++) {
            int k = k0 + i;
            Bs[i][tid] = (k < D1) ? W1[(size_t)k * LSZ + tid] : 0.f;
        }
        __syncthreads();
#pragma unroll
        for (int kk = 0; kk < 16; kk++) {
            float4 a0 = *(const float4*)&As[kk][trow * 8];
            float4 a1v_ = *(const float4*)&As[kk][trow * 8 + 4];
            float4 b0 = *(const float4*)&Bs[kk][tcol * 8];
            float4 b1_ = *(const float4*)&Bs[kk][tcol * 8 + 4];
            float a[8] = {a0.x, a0.y, a0.z, a0.w, a1v_.x, a1v_.y, a1v_.z, a1v_.w};
            float b[8] = {b0.x, b0.y, b0.z, b0.w, b1_.x, b1_.y, b1_.z, b1_.w};
#pragma unroll
            for (int m = 0; m < 8; m++)
#pragma unroll
                for (int n = 0; n < 8; n++)
                    acc[m][n] = fmaf(a[m], b[n], acc[m][n]);
        }
        __syncthreads();
    }

    if (MODE == 0) {
        // ---- BN stats epilogue: column sum & sumsq ----
        float s[8], q[8];
#pragma unroll
        for (int j = 0; j < 8; j++) { s[j] = 0.f; q[j] = 0.f; }
#pragma unroll
        for (int m = 0; m < 8; m++)
#pragma unroll
            for (int j = 0; j < 8; j++) {
                float v = acc[m][j];
                s[j] += v; q[j] += v * v;
            }
        // stage per-rowgroup partials in Bs (rows 0..7 = sum, 8..15 = sumsq)
#pragma unroll
        for (int j = 0; j < 8; j++) {
            Bs[trow][tcol * 8 + j]     = s[j];
            Bs[8 + trow][tcol * 8 + j] = q[j];
        }
        __syncthreads();
        float ts = 0.f, tq = 0.f;
#pragma unroll
        for (int g = 0; g < 8; g++) {
            ts += Bs[g][tid];
            tq += Bs[8 + g][tid];
        }
        atomicAdd(&colsum[tid], ts);
        atomicAdd(&colsq[tid], tq);
    } else {
        // ---- aggregate epilogue: affine+relu, run-merge by destination ----
        float A[8], B[8];
#pragma unroll
        for (int j = 0; j < 8; j++) {
            A[j] = a1[tcol * 8 + j];
            B[j] = b1n[tcol * 8 + j];
        }
        const int rbase = trow * 8;
        int cur = destS[rbase];
        float run[8];
#pragma unroll
        for (int j = 0; j < 8; j++)
            run[j] = fmaxf(fmaf(acc[0][j], A[j], B[j]), 0.f);
#pragma unroll
        for (int m = 1; m < 8; m++) {
            int d = destS[rbase + m];
            if (d != cur) {
                size_t bse = (size_t)cur * LSZ + tcol * 8;
#pragma unroll
                for (int j = 0; j < 8; j++) atomicAdd(&aggsum[bse + j], run[j]);
                cur = d;
#pragma unroll
                for (int j = 0; j < 8; j++)
                    run[j] = fmaxf(fmaf(acc[m][j], A[j], B[j]), 0.f);
            } else {
#pragma unroll
                for (int j = 0; j < 8; j++)
                    run[j] += fmaxf(fmaf(acc[m][j], A[j], B[j]), 0.f);
            }
        }
        size_t bse = (size_t)cur * LSZ + tcol * 8;
#pragma unroll
        for (int j = 0; j < 8; j++) atomicAdd(&aggsum[bse + j], run[j]);
    }
}

// ---------------------------------------------------------------------------
// Column sum / sumsq over a [rows x cols] row-major matrix (BN stats, Y2)
// ---------------------------------------------------------------------------
__global__ __launch_bounds__(256) void colstats_kernel(
    const float* __restrict__ Y, int rows, int cols, int rows_per_block,
    float* __restrict__ sum, float* __restrict__ sumsq)
{
    int r0 = blockIdx.x * rows_per_block;
    int r1 = min(r0 + rows_per_block, rows);
    for (int c = threadIdx.x; c < cols; c += 256) {
        float s = 0.f, s2 = 0.f;
        for (int r = r0; r < r1; r++) {
            float v = Y[(size_t)r * cols + c];
            s += v; s2 += v * v;
        }
        atomicAdd(&sum[c], s);
        atomicAdd(&sumsq[c], s2);
    }
}

__global__ void finalize_kernel(
    const float* __restrict__ sum, const float* __restrict__ sumsq,
    const float* __restrict__ gamma, const float* __restrict__ beta,
    float* __restrict__ a, float* __restrict__ b, int cols, float invn)
{
    int c = blockIdx.x * blockDim.x + threadIdx.x;
    if (c < cols) {
        float mu  = sum[c] * invn;
        float var = fmaxf(sumsq[c] * invn - mu * mu, 0.f);
        float s   = gamma[c] * rsqrtf(var + BN_EPS);
        a[c] = s;
        b[c] = beta[c] - mu * s;
    }
}

// ---------------------------------------------------------------------------
// CSR build: histogram, single-block scan, slot fill
// ---------------------------------------------------------------------------
__global__ void hist_kernel(const int* __restrict__ colE, int* __restrict__ cnt)
{
    int e = blockIdx.x * 256 + threadIdx.x;
    if (e < NE) atomicAdd(&cnt[colE[e]], 1);
}

__global__ __launch_bounds__(1024) void scan_kernel(
    const int* __restrict__ cnt, int* __restrict__ start, int n)
{
    __shared__ int wsum[16];
    __shared__ int carry_s;
    int tid = threadIdx.x;
    if (tid == 0) { carry_s = 0; start[0] = 0; }
    __syncthreads();
    for (int base = 0; base < n; base += 1024) {
        int i = base + tid;
        int v = (i < n) ? cnt[i] : 0;
        int lane = tid & 63, wave = tid >> 6;
        int sv = v;
#pragma unroll
        for (int off = 1; off < 64; off <<= 1) {
            int t = __shfl_up(sv, off);
            if (lane >= off) sv += t;
        }
        __syncthreads();               // prev iteration readers done
        if (lane == 63) wsum[wave] = sv;
        __syncthreads();               // wsum ready
        int carry = carry_s;
        int woff = carry;
        for (int w = 0; w < wave; w++) woff += wsum[w];
        int incl = sv + woff;
        if (i < n) start[i + 1] = incl;
        int total = carry;
#pragma unroll
        for (int w = 0; w < 16; w++) total += wsum[w];
        __syncthreads();               // all reads of carry_s / wsum done
        if (tid == 0) carry_s = total;
    }
}

__global__ void fill_kernel(const int* __restrict__ colE, const int* __restrict__ start,
                            int* __restrict__ cursor, int* __restrict__ eidx)
{
    int e = blockIdx.x * 256 + threadIdx.x;
    if (e < NE) {
        int c = colE[e];
        int p = start[c] + atomicAdd(&cursor[c], 1);
        eidx[p] = e;
    }
}

// ---------------------------------------------------------------------------
// agg[n,c] = aggsum[n,c] / max(cnt[n],1)   (in-place, float4)
// ---------------------------------------------------------------------------
__global__ __launch_bounds__(256) void divcnt_kernel(
    float* __restrict__ agg, const int* __restrict__ cnt)
{
    int f = blockIdx.x * 256 + threadIdx.x;         // float4 index
    int n = f >> 6;                                  // 64 float4 per row (256 cols)
    if (n < NN) {
        float inv = 1.0f / fmaxf((float)cnt[n], 1.0f);
        float4* p = (float4*)agg + f;
        float4 v = *p;
        v.x *= inv; v.y *= inv; v.z *= inv; v.w *= inv;
        *p = v;
    }
}

// ---------------------------------------------------------------------------
// GEMM2: Y2[n,c] = sum_k h2[n,k] * W2[k,c]   (bias cancelled by BN)
//   h2[n,:] = [ x[n,0:128], batch[n], agg[n,0:256] ]
// Tile 64x128, BK=16; 8x4 per thread; grid.y covers 385 cols.
// ---------------------------------------------------------------------------
__global__ __launch_bounds__(256) void gemm2_kernel(
    const float* __restrict__ x, const int* __restrict__ batch,
    const float* __restrict__ agg, const float* __restrict__ W2,
    float* __restrict__ Y2)
{
    __shared__ float As[16][68];
    __shared__ float Bs[16][128];
    const int tid = threadIdx.x;
    const int n0 = blockIdx.x * 64;
    const int c0 = blockIdx.y * 128;
    const int tcol = tid & 31;
    const int trow = tid >> 5;

    float acc[8][4];
#pragma unroll
    for (int i = 0; i < 8; i++)
#pragma unroll
        for (int j = 0; j < 4; j++) acc[i][j] = 0.f;

    for (int k0 = 0; k0 < D2; k0 += 16) {
#pragma unroll
        for (int i = 0; i < 4; i++) {
            int lin = tid + i * 256;
            int r = lin >> 4, kk = lin & 15;
            int n = n0 + r, k = k0 + kk;
            float v = 0.f;
            if (n < NN) {
                if (k < NF)       v = x[(size_t)n * NF + k];
                else if (k == NF) v = (float)batch[n];
                else if (k < D2)  v = agg[(size_t)n * LSZ + (k - NF - 1)];
            }
            As[kk][r] = v;
        }
#pragma unroll
        for (int i = 0; i < 8; i++) {
            int lin = tid + i * 256;
            int kk = lin >> 7, c = lin & 127;
            int k = k0 + kk, cc = c0 + c;
            Bs[kk][c] = (k < D2 && cc < D2) ? W2[(size_t)k * D2 + cc] : 0.f;
        }
        __syncthreads();
#pragma unroll
        for (int kk = 0; kk < 16; kk++) {
            float4 a0 = *(const float4*)&As[kk][trow * 8];
            float4 a1 = *(const float4*)&As[kk][trow * 8 + 4];
            float4 b0 = *(const float4*)&Bs[kk][tcol * 4];
            float a[8] = {a0.x, a0.y, a0.z, a0.w, a1.x, a1.y, a1.z, a1.w};
            float b[4] = {b0.x, b0.y, b0.z, b0.w};
#pragma unroll
            for (int m = 0; m < 8; m++)
#pragma unroll
                for (int n = 0; n < 4; n++)
                    acc[m][n] = fmaf(a[m], b[n], acc[m][n]);
        }
        __syncthreads();
    }
#pragma unroll
    for (int m = 0; m < 8; m++) {
        int n = n0 + trow * 8 + m;
        if (n < NN) {
#pragma unroll
            for (int j = 0; j < 4; j++) {
                int cc = c0 + tcol * 4 + j;
                if (cc < D2) Y2[(size_t)n * D2 + cc] = acc[m][j];
            }
        }
    }
}

// ---------------------------------------------------------------------------
// GEMM3: out[n,c] = relu( sum_k relu(Y2[n,k]*a2[k]+b2n[k]) * W3[k,c] + b3[c] )
// ---------------------------------------------------------------------------
__global__ __launch_bounds__(256) void gemm3_kernel(
    const float* __restrict__ Y2, const float* __restrict__ a2,
    const float* __restrict__ b2n, const float* __restrict__ W3,
    const float* __restrict__ b3, float* __restrict__ out)
{
    __shared__ float As[16][68];
    __shared__ float Bs[16][128];
    const int tid = threadIdx.x;
    const int n0 = blockIdx.x * 64;
    const int tcol = tid & 31;
    const int trow = tid >> 5;

    float acc[8][4];
#pragma unroll
    for (int i = 0; i < 8; i++)
#pragma unroll
        for (int j = 0; j < 4; j++) acc[i][j] = 0.f;

    for (int k0 = 0; k0 < D2; k0 += 16) {
#pragma unroll
        for (int i = 0; i < 4; i++) {
            int lin = tid + i * 256;
            int r = lin >> 4, kk = lin & 15;
            int n = n0 + r, k = k0 + kk;
            float v = 0.f;
            if (n < NN && k < D2) {
                v = Y2[(size_t)n * D2 + k];
                v = fmaf(v, a2[k], b2n[k]);
                v = fmaxf(v, 0.f);
            }
            As[kk][r] = v;
        }
#pragma unroll
        for (int i = 0; i < 8; i++) {
            int lin = tid + i * 256;
            int kk = lin >> 7, c = lin & 127;
            int k = k0 + kk;
            Bs[kk][c] = (k < D2) ? W3[(size_t)k * NF + c] : 0.f;
        }
        __syncthreads();
#pragma unroll
        for (int kk = 0; kk < 16; kk++) {
            float4 a0 = *(const float4*)&As[kk][trow * 8];
            float4 a1 = *(const float4*)&As[kk][trow * 8 + 4];
            float4 b0 = *(const float4*)&Bs[kk][tcol * 4];
            float a[8] = {a0.x, a0.y, a0.z, a0.w, a1.x, a1.y, a1.z, a1.w};
            float b[4] = {b0.x, b0.y, b0.z, b0.w};
#pragma unroll
            for (int m = 0; m < 8; m++)
#pragma unroll
                for (int n = 0; n < 4; n++)
                    acc[m][n] = fmaf(a[m], b[n], acc[m][n]);
        }
        __syncthreads();
    }
#pragma unroll
    for (int m = 0; m < 8; m++) {
        int n = n0 + trow * 8 + m;
        if (n < NN) {
            int c = tcol * 4;
            float4 r;
            r.x = fmaxf(acc[m][0] + b3[c + 0], 0.f);
            r.y = fmaxf(acc[m][1] + b3[c + 1], 0.f);
            r.z = fmaxf(acc[m][2] + b3[c + 2], 0.f);
            r.w = fmaxf(acc[m][3] + b3[c + 3], 0.f);
            *(float4*)&out[(size_t)n * NF + c] = r;
        }
    }
}

// ---------------------------------------------------------------------------
extern "C" void kernel_launch(void* const* d_in, const int* in_sizes, int n_in,
                              void* d_out, int out_size, void* d_ws, size_t ws_size,
                              hipStream_t stream)
{
    const float* x         = (const float*)d_in[0];
    const int*   edge_idx  = (const int*)d_in[1];
    const float* edge_attr = (const float*)d_in[2];
    // d_in[3] = u : unused by the reference
    const int*   batch     = (const int*)d_in[4];
    const float* W1        = (const float*)d_in[5];
    // d_in[6] = b1 : cancelled by BatchNorm
    const float* g1        = (const float*)d_in[7];
    const float* be1       = (const float*)d_in[8];
    const float* W2        = (const float*)d_in[9];
    // d_in[10] = b2 : cancelled by BatchNorm
    const float* g2        = (const float*)d_in[11];
    const float* be2       = (const float*)d_in[12];
    const float* W3        = (const float*)d_in[13];
    const float* b3        = (const float*)d_in[14];
    float* out = (float*)d_out;

    const int* rowE = edge_idx;        // edge_index[0]
    const int* colE = edge_idx + NE;   // edge_index[1]

    // ---- workspace layout (~132 MB total) ----
    char* ws = (char*)d_ws;
    size_t off = 0;
    auto alloc = [&](size_t bytes) -> void* {
        void* p = ws + off;
        off += (bytes + 255) & ~(size_t)255;
        return p;
    };
    float* Y2    = (float*)alloc((size_t)NN * D2 * 4);    // 77.0 MB
    int*   eidx  = (int*)  alloc((size_t)NE * 4);         //  3.2 MB
    int*   start = (int*)  alloc((size_t)(NN + 1) * 4);
    float* a1    = (float*)alloc(LSZ * 4);
    float* b1n   = (float*)alloc(LSZ * 4);
    float* a2    = (float*)alloc(D2 * 4);
    float* b2n   = (float*)alloc(D2 * 4);
    size_t zoff = off;                                     // ---- zero region ----
    float* agg     = (float*)alloc((size_t)NN * LSZ * 4); // 51.2 MB (aggsum -> agg)
    int*   cnt     = (int*)  alloc((size_t)NN * 4);
    int*   cursor  = (int*)  alloc((size_t)NN * 4);
    float* colsum1 = (float*)alloc(LSZ * 4);
    float* colsq1  = (float*)alloc(LSZ * 4);
    float* colsum2 = (float*)alloc(D2 * 4);
    float* colsq2  = (float*)alloc(D2 * 4);
    size_t total = off;
    if (ws_size < total) return;  // still guard; now only ~132 MB needed

    hipMemsetAsync(ws + zoff, 0, total - zoff, stream);

    // CSR by destination node
    hist_kernel<<<NE / 256, 256, 0, stream>>>(colE, cnt);
    scan_kernel<<<1, 1024, 0, stream>>>(cnt, start, NN);
    fill_kernel<<<NE / 256, 256, 0, stream>>>(colE, start, cursor, eidx);

    // edge MLP pass A: GEMM + fused BN stats (no Y1 store)
    gemm1_core<0><<<NE / 64, 256, 0, stream>>>(
        x, rowE, colE, batch, edge_attr, W1,
        nullptr, nullptr, nullptr, colsum1, colsq1, nullptr);
    finalize_kernel<<<1, 256, 0, stream>>>(colsum1, colsq1, g1, be1, a1, b1n, LSZ, 1.0f / NE);

    // edge MLP pass B: recompute in CSR order, affine+relu, scatter-add
    gemm1_core<1><<<NE / 64, 256, 0, stream>>>(
        x, rowE, colE, batch, edge_attr, W1,
        eidx, a1, b1n, nullptr, nullptr, agg);
    divcnt_kernel<<<(NN * LSZ / 4 + 255) / 256, 256, 0, stream>>>(agg, cnt);

    // node MLP
    gemm2_kernel<<<dim3((NN + 63) / 64, 4), 256, 0, stream>>>(x, batch, agg, W2, Y2);
    colstats_kernel<<<(NN + 511) / 512, 256, 0, stream>>>(Y2, NN, D2, 512, colsum2, colsq2);
    finalize_kernel<<<2, 256, 0, stream>>>(colsum2, colsq2, g2, be2, a2, b2n, D2, 1.0f / NN);

    // output linear (BN+ReLU fused into A load; ReLU+b3 in epilogue)
    gemm3_kernel<<<dim3((NN + 63) / 64, 1), 256, 0, stream>>>(Y2, a2, b2n, W3, b3, out);
}

// Round 3
// 2455.150 us; speedup vs baseline: 2.4413x; 2.4413x over previous
//
#include <hip/hip_runtime.h>

#define NN 50000      // nodes
#define NE 800000     // edges
#define NF 128        // node features
#define EF 64         // edge features
#define LSZ 256       // layer size
#define D1 193        // NF+EF+1
#define D2 385        // NF+LSZ+1
#define KP 224        // D1 padded to 7*32
#define NSTEP 7       // K steps of 32
#define BN_EPS 1e-5f

typedef float  f32x4 __attribute__((ext_vector_type(4)));
typedef short  s16x8 __attribute__((ext_vector_type(8)));

__device__ __forceinline__ unsigned short f2bf(float f) {
    unsigned u = __float_as_uint(f);
    u += 0x7FFFu + ((u >> 16) & 1u);   // RNE
    return (unsigned short)(u >> 16);
}

// ===========================================================================
// Pre-pack W1 (fp32 [193][256]) into MFMA B-fragment order, K padded to 224:
//   W1p[((s*16 + i)*64 + lane)*8 + j] = bf16( W1[k][n] ), k=s*32+(lane>>4)*8+j,
//   n=16*i+(lane&15); zero for k>=193.  Total 7*16*64*8 = 57344 bf16 (112 KB).
// ===========================================================================
__global__ void prep_w1p_kernel(const float* __restrict__ W1,
                                unsigned short* __restrict__ W1p)
{
    int t = blockIdx.x * 256 + threadIdx.x;          // one thread per fragment
    if (t >= NSTEP * 16 * 64) return;
    int lane = t & 63, si = t >> 6;
    int i = si & 15, s = si >> 4;
    int q = lane >> 4, n = (i << 4) + (lane & 15);
    unsigned short v[8];
#pragma unroll
    for (int j = 0; j < 8; j++) {
        int k = s * 32 + q * 8 + j;
        v[j] = (k < D1) ? f2bf(W1[(size_t)k * LSZ + n]) : (unsigned short)0;
    }
    *(uint4*)&W1p[(size_t)t * 8] = *(const uint4*)v;
}

// ===========================================================================
// GEMM1 via bf16 MFMA, no LDS, no barriers.
// Block: 256 thr = 4 waves; wave computes 16 edges x 256 cols.
//   h[e,:] = [ x[row[e],0:128], batch[row[e]], edge_attr[e,0:64], 0-pad ]
// MODE 0: natural order; epilogue = col sum/sumsq -> bucketed atomics
// MODE 1: CSR order (eidx); epilogue = BN affine + ReLU + run-merged
//         scatter-add into aggsum[dest,:]
// ===========================================================================
template <int MODE>
__global__ __launch_bounds__(256) void gemm1_mfma(
    const float* __restrict__ x, const int* __restrict__ rowi,
    const int* __restrict__ colE, const int* __restrict__ batch,
    const float* __restrict__ ea, const unsigned short* __restrict__ W1p,
    const int* __restrict__ eidx,
    const float* __restrict__ a1, const float* __restrict__ b1n,
    float* __restrict__ colsum_b, float* __restrict__ colsq_b,
    float* __restrict__ aggsum)
{
    const int tid  = threadIdx.x;
    const int lane = tid & 63, wave = tid >> 6;
    const int quad = lane >> 4, l15 = lane & 15;
    const int slot = blockIdx.x * 64 + wave * 16 + l15;

    const int e   = (MODE == 1) ? eidx[slot] : slot;
    const int row = rowi[e];
    const float bval = (float)batch[row];
    int dst = 0;
    if (MODE == 1) dst = colE[e];

    const float* xr = x  + (size_t)row * NF;
    const float* er = ea + (size_t)e * EF;
    const s16x8* Bp = (const s16x8*)W1p;

    f32x4 acc[16];
#pragma unroll
    for (int i = 0; i < 16; i++) acc[i] = (f32x4){0.f, 0.f, 0.f, 0.f};

    // ---- x region: K-steps 0..3 (k = s*32 + quad*8 + j, all < 128) ----
#pragma unroll
    for (int s = 0; s < 4; s++) {
        const float4* xp = (const float4*)(xr + s * 32 + quad * 8);
        float4 x0 = xp[0], x1 = xp[1];
        s16x8 af;
        af[0] = (short)f2bf(x0.x); af[1] = (short)f2bf(x0.y);
        af[2] = (short)f2bf(x0.z); af[3] = (short)f2bf(x0.w);
        af[4] = (short)f2bf(x1.x); af[5] = (short)f2bf(x1.y);
        af[6] = (short)f2bf(x1.z); af[7] = (short)f2bf(x1.w);
        s16x8 bf[16];
#pragma unroll
        for (int i = 0; i < 16; i++) bf[i] = Bp[(size_t)(s * 16 + i) * 64 + lane];
#pragma unroll
        for (int i = 0; i < 16; i++)
            acc[i] = __builtin_amdgcn_mfma_f32_16x16x32_bf16(af, bf[i], acc[i], 0, 0, 0);
    }
    // ---- tail region: K-steps 4..6 (k = 128 batch | 129..192 ea | pad 0) ----
#pragma unroll
    for (int s = 4; s < 7; s++) {
        const int kb = s * 32 + quad * 8;
        s16x8 af;
#pragma unroll
        for (int j = 0; j < 8; j++) {
            int k = kb + j;
            float v;
            if (k == NF)                  v = bval;
            else if (k > NF && k < D1)    v = er[k - NF - 1];
            else                          v = 0.f;
            af[j] = (short)f2bf(v);
        }
        s16x8 bf[16];
#pragma unroll
        for (int i = 0; i < 16; i++) bf[i] = Bp[(size_t)(s * 16 + i) * 64 + lane];
#pragma unroll
        for (int i = 0; i < 16; i++)
            acc[i] = __builtin_amdgcn_mfma_f32_16x16x32_bf16(af, bf[i], acc[i], 0, 0, 0);
    }

    // C/D layout: element r of lane holds C[row = quad*4 + r][col = 16*i + l15]
    if (MODE == 0) {
        const int bucket = blockIdx.x & 63;
#pragma unroll
        for (int i = 0; i < 16; i++) {
            float s = acc[i][0] + acc[i][1] + acc[i][2] + acc[i][3];
            float q = acc[i][0]*acc[i][0] + acc[i][1]*acc[i][1]
                    + acc[i][2]*acc[i][2] + acc[i][3]*acc[i][3];
            s += __shfl_xor(s, 16); s += __shfl_xor(s, 32);
            q += __shfl_xor(q, 16); q += __shfl_xor(q, 32);
            if (quad == 0) {
                int c = (i << 4) + l15;
                atomicAdd(&colsum_b[bucket * LSZ + c], s);
                atomicAdd(&colsq_b [bucket * LSZ + c], q);
            }
        }
    } else {
        // dest of tile rows quad*4+r (lanes 0..15 hold slots 0..15 of this wave)
        int d[4];
#pragma unroll
        for (int r = 0; r < 4; r++) d[r] = __shfl(dst, quad * 4 + r);
#pragma unroll
        for (int i = 0; i < 16; i++) {
            const int c = (i << 4) + l15;
            const float Ac = a1[c], Bc = b1n[c];
            int   cur = d[0];
            float run = fmaxf(fmaf(acc[i][0], Ac, Bc), 0.f);
#pragma unroll
            for (int r = 1; r < 4; r++) {
                float y = fmaxf(fmaf(acc[i][r], Ac, Bc), 0.f);
                if (d[r] != cur) {
                    atomicAdd(&aggsum[(size_t)cur * LSZ + c], run);
                    cur = d[r]; run = y;
                } else run += y;
            }
            atomicAdd(&aggsum[(size_t)cur * LSZ + c], run);
        }
    }
}

// ---------------------------------------------------------------------------
// finalize layer-1 BN: reduce 64 buckets, fold gamma/beta into affine a,b
// ---------------------------------------------------------------------------
__global__ void finalize1_kernel(
    const float* __restrict__ colsum_b, const float* __restrict__ colsq_b,
    const float* __restrict__ gamma, const float* __restrict__ beta,
    float* __restrict__ a, float* __restrict__ b)
{
    int c = threadIdx.x;  // 256
    float s = 0.f, q = 0.f;
    for (int bk = 0; bk < 64; bk++) {
        s += colsum_b[bk * LSZ + c];
        q += colsq_b [bk * LSZ + c];
    }
    float mu  = s * (1.0f / NE);
    float var = fmaxf(q * (1.0f / NE) - mu * mu, 0.f);
    float sc  = gamma[c] * rsqrtf(var + BN_EPS);
    a[c] = sc;
    b[c] = beta[c] - mu * sc;
}

// ---------------------------------------------------------------------------
// Column sum / sumsq over a [rows x cols] row-major matrix (BN stats, Y2)
// ---------------------------------------------------------------------------
__global__ __launch_bounds__(256) void colstats_kernel(
    const float* __restrict__ Y, int rows, int cols, int rows_per_block,
    float* __restrict__ sum, float* __restrict__ sumsq)
{
    int r0 = blockIdx.x * rows_per_block;
    int r1 = min(r0 + rows_per_block, rows);
    for (int c = threadIdx.x; c < cols; c += 256) {
        float s = 0.f, s2 = 0.f;
        for (int r = r0; r < r1; r++) {
            float v = Y[(size_t)r * cols + c];
            s += v; s2 += v * v;
        }
        atomicAdd(&sum[c], s);
        atomicAdd(&sumsq[c], s2);
    }
}

__global__ void finalize_kernel(
    const float* __restrict__ sum, const float* __restrict__ sumsq,
    const float* __restrict__ gamma, const float* __restrict__ beta,
    float* __restrict__ a, float* __restrict__ b, int cols, float invn)
{
    int c = blockIdx.x * blockDim.x + threadIdx.x;
    if (c < cols) {
        float mu  = sum[c] * invn;
        float var = fmaxf(sumsq[c] * invn - mu * mu, 0.f);
        float s   = gamma[c] * rsqrtf(var + BN_EPS);
        a[c] = s;
        b[c] = beta[c] - mu * s;
    }
}

// ---------------------------------------------------------------------------
// CSR build: histogram, single-block scan, slot fill
// ---------------------------------------------------------------------------
__global__ void hist_kernel(const int* __restrict__ colE, int* __restrict__ cnt)
{
    int e = blockIdx.x * 256 + threadIdx.x;
    if (e < NE) atomicAdd(&cnt[colE[e]], 1);
}

__global__ __launch_bounds__(1024) void scan_kernel(
    const int* __restrict__ cnt, int* __restrict__ start, int n)
{
    __shared__ int wsum[16];
    __shared__ int carry_s;
    int tid = threadIdx.x;
    if (tid == 0) { carry_s = 0; start[0] = 0; }
    __syncthreads();
    for (int base = 0; base < n; base += 1024) {
        int i = base + tid;
        int v = (i < n) ? cnt[i] : 0;
        int lane = tid & 63, wave = tid >> 6;
        int sv = v;
#pragma unroll
        for (int off = 1; off < 64; off <<= 1) {
            int t = __shfl_up(sv, off);
            if (lane >= off) sv += t;
        }
        __syncthreads();
        if (lane == 63) wsum[wave] = sv;
        __syncthreads();
        int carry = carry_s;
        int woff = carry;
        for (int w = 0; w < wave; w++) woff += wsum[w];
        int incl = sv + woff;
        if (i < n) start[i + 1] = incl;
        int total = carry;
#pragma unroll
        for (int w = 0; w < 16; w++) total += wsum[w];
        __syncthreads();
        if (tid == 0) carry_s = total;
    }
}

__global__ void fill_kernel(const int* __restrict__ colE, const int* __restrict__ start,
                            int* __restrict__ cursor, int* __restrict__ eidx)
{
    int e = blockIdx.x * 256 + threadIdx.x;
    if (e < NE) {
        int c = colE[e];
        int p = start[c] + atomicAdd(&cursor[c], 1);
        eidx[p] = e;
    }
}

// ---------------------------------------------------------------------------
// agg[n,c] = aggsum[n,c] / max(cnt[n],1)   (in-place, float4)
// ---------------------------------------------------------------------------
__global__ __launch_bounds__(256) void divcnt_kernel(
    float* __restrict__ agg, const int* __restrict__ cnt)
{
    int f = blockIdx.x * 256 + threadIdx.x;
    int n = f >> 6;                       // 64 float4 per 256-col row
    if (n < NN) {
        float inv = 1.0f / fmaxf((float)cnt[n], 1.0f);
        float4* p = (float4*)agg + f;
        float4 v = *p;
        v.x *= inv; v.y *= inv; v.z *= inv; v.w *= inv;
        *p = v;
    }
}

// ---------------------------------------------------------------------------
// GEMM2 (fp32): Y2[n,c] = sum_k h2[n,k] * W2[k,c]
//   h2[n,:] = [ x[n,0:128], batch[n], agg[n,0:256] ]
// ---------------------------------------------------------------------------
__global__ __launch_bounds__(256) void gemm2_kernel(
    const float* __restrict__ x, const int* __restrict__ batch,
    const float* __restrict__ agg, const float* __restrict__ W2,
    float* __restrict__ Y2)
{
    __shared__ float As[16][68];
    __shared__ float Bs[16][128];
    const int tid = threadIdx.x;
    const int n0 = blockIdx.x * 64;
    const int c0 = blockIdx.y * 128;
    const int tcol = tid & 31;
    const int trow = tid >> 5;

    float acc[8][4];
#pragma unroll
    for (int i = 0; i < 8; i++)
#pragma unroll
        for (int j = 0; j < 4; j++) acc[i][j] = 0.f;

    for (int k0 = 0; k0 < D2; k0 += 16) {
#pragma unroll
        for (int i = 0; i < 4; i++) {
            int lin = tid + i * 256;
            int r = lin >> 4, kk = lin & 15;
            int n = n0 + r, k = k0 + kk;
            float v = 0.f;
            if (n < NN) {
                if (k < NF)       v = x[(size_t)n * NF + k];
                else if (k == NF) v = (float)batch[n];
                else if (k < D2)  v = agg[(size_t)n * LSZ + (k - NF - 1)];
            }
            As[kk][r] = v;
        }
#pragma unroll
        for (int i = 0; i < 8; i++) {
            int lin = tid + i * 256;
            int kk = lin >> 7, c = lin & 127;
            int k = k0 + kk, cc = c0 + c;
            Bs[kk][c] = (k < D2 && cc < D2) ? W2[(size_t)k * D2 + cc] : 0.f;
        }
        __syncthreads();
#pragma unroll
        for (int kk = 0; kk < 16; kk++) {
            float4 a0 = *(const float4*)&As[kk][trow * 8];
            float4 a1 = *(const float4*)&As[kk][trow * 8 + 4];
            float4 b0 = *(const float4*)&Bs[kk][tcol * 4];
            float a[8] = {a0.x, a0.y, a0.z, a0.w, a1.x, a1.y, a1.z, a1.w};
            float b[4] = {b0.x, b0.y, b0.z, b0.w};
#pragma unroll
            for (int m = 0; m < 8; m++)
#pragma unroll
                for (int n = 0; n < 4; n++)
                    acc[m][n] = fmaf(a[m], b[n], acc[m][n]);
        }
        __syncthreads();
    }
#pragma unroll
    for (int m = 0; m < 8; m++) {
        int n = n0 + trow * 8 + m;
        if (n < NN) {
#pragma unroll
            for (int j = 0; j < 4; j++) {
                int cc = c0 + tcol * 4 + j;
                if (cc < D2) Y2[(size_t)n * D2 + cc] = acc[m][j];
            }
        }
    }
}

// ---------------------------------------------------------------------------
// GEMM3 (fp32): out[n,c] = relu( sum_k relu(Y2[n,k]*a2[k]+b2n[k])*W3[k,c] + b3[c] )
// ---------------------------------------------------------------------------
__global__ __launch_bounds__(256) void gemm3_kernel(
    const float* __restrict__ Y2, const float* __restrict__ a2,
    const float* __restrict__ b2n, const float* __restrict__ W3,
    const float* __restrict__ b3, float* __restrict__ out)
{
    __shared__ float As[16][68];
    __shared__ float Bs[16][128];
    const int tid = threadIdx.x;
    const int n0 = blockIdx.x * 64;
    const int tcol = tid & 31;
    const int trow = tid >> 5;

    float acc[8][4];
#pragma unroll
    for (int i = 0; i < 8; i++)
#pragma unroll
        for (int j = 0; j < 4; j++) acc[i][j] = 0.f;

    for (int k0 = 0; k0 < D2; k0 += 16) {
#pragma unroll
        for (int i = 0; i < 4; i++) {
            int lin = tid + i * 256;
            int r = lin >> 4, kk = lin & 15;
            int n = n0 + r, k = k0 + kk;
            float v = 0.f;
            if (n < NN && k < D2) {
                v = Y2[(size_t)n * D2 + k];
                v = fmaf(v, a2[k], b2n[k]);
                v = fmaxf(v, 0.f);
            }
            As[kk][r] = v;
        }
#pragma unroll
        for (int i = 0; i < 8; i++) {
            int lin = tid + i * 256;
            int kk = lin >> 7, c = lin & 127;
            int k = k0 + kk;
            Bs[kk][c] = (k < D2) ? W3[(size_t)k * NF + c] : 0.f;
        }
        __syncthreads();
#pragma unroll
        for (int kk = 0; kk < 16; kk++) {
            float4 a0 = *(const float4*)&As[kk][trow * 8];
            float4 a1 = *(const float4*)&As[kk][trow * 8 + 4];
            float4 b0 = *(const float4*)&Bs[kk][tcol * 4];
            float a[8] = {a0.x, a0.y, a0.z, a0.w, a1.x, a1.y, a1.z, a1.w};
            float b[4] = {b0.x, b0.y, b0.z, b0.w};
#pragma unroll
            for (int m = 0; m < 8; m++)
#pragma unroll
                for (int n = 0; n < 4; n++)
                    acc[m][n] = fmaf(a[m], b[n], acc[m][n]);
        }
        __syncthreads();
    }
#pragma unroll
    for (int m = 0; m < 8; m++) {
        int n = n0 + trow * 8 + m;
        if (n < NN) {
            int c = tcol * 4;
            float4 r;
            r.x = fmaxf(acc[m][0] + b3[c + 0], 0.f);
            r.y = fmaxf(acc[m][1] + b3[c + 1], 0.f);
            r.z = fmaxf(acc[m][2] + b3[c + 2], 0.f);
            r.w = fmaxf(acc[m][3] + b3[c + 3], 0.f);
            *(float4*)&out[(size_t)n * NF + c] = r;
        }
    }
}

// ---------------------------------------------------------------------------
extern "C" void kernel_launch(void* const* d_in, const int* in_sizes, int n_in,
                              void* d_out, int out_size, void* d_ws, size_t ws_size,
                              hipStream_t stream)
{
    const float* x         = (const float*)d_in[0];
    const int*   edge_idx  = (const int*)d_in[1];
    const float* edge_attr = (const float*)d_in[2];
    // d_in[3] = u : unused by the reference
    const int*   batch     = (const int*)d_in[4];
    const float* W1        = (const float*)d_in[5];
    // d_in[6] = b1 : cancelled by BatchNorm
    const float* g1        = (const float*)d_in[7];
    const float* be1       = (const float*)d_in[8];
    const float* W2        = (const float*)d_in[9];
    // d_in[10] = b2 : cancelled by BatchNorm
    const float* g2        = (const float*)d_in[11];
    const float* be2       = (const float*)d_in[12];
    const float* W3        = (const float*)d_in[13];
    const float* b3        = (const float*)d_in[14];
    float* out = (float*)d_out;

    const int* rowE = edge_idx;        // edge_index[0]
    const int* colE = edge_idx + NE;   // edge_index[1]

    // ---- workspace layout (~132.3 MB) ----
    char* ws = (char*)d_ws;
    size_t off = 0;
    auto alloc = [&](size_t bytes) -> void* {
        void* p = ws + off;
        off += (bytes + 255) & ~(size_t)255;
        return p;
    };
    float*          Y2    = (float*)alloc((size_t)NN * D2 * 4);     // 77.0 MB
    int*            eidx  = (int*)  alloc((size_t)NE * 4);          //  3.2 MB
    int*            start = (int*)  alloc((size_t)(NN + 1) * 4);
    float*          a1    = (float*)alloc(LSZ * 4);
    float*          b1n   = (float*)alloc(LSZ * 4);
    float*          a2    = (float*)alloc(D2 * 4);
    float*          b2n   = (float*)alloc(D2 * 4);
    unsigned short* W1p   = (unsigned short*)alloc((size_t)NSTEP * 16 * 64 * 8 * 2); // 112 KB
    size_t zoff = off;                                               // ---- zero region ----
    float* agg      = (float*)alloc((size_t)NN * LSZ * 4);          // 51.2 MB
    int*   cnt      = (int*)  alloc((size_t)NN * 4);
    int*   cursor   = (int*)  alloc((size_t)NN * 4);
    float* colsum_b = (float*)alloc(64 * LSZ * 4);                  // 64 KB
    float* colsq_b  = (float*)alloc(64 * LSZ * 4);
    float* colsum2  = (float*)alloc(D2 * 4);
    float* colsq2   = (float*)alloc(D2 * 4);
    size_t total = off;
    if (ws_size < total) return;

    hipMemsetAsync(ws + zoff, 0, total - zoff, stream);

    // pre-pack W1 into fragment order
    prep_w1p_kernel<<<(NSTEP * 16 * 64 + 255) / 256, 256, 0, stream>>>(W1, W1p);

    // CSR by destination node
    hist_kernel<<<NE / 256, 256, 0, stream>>>(colE, cnt);
    scan_kernel<<<1, 1024, 0, stream>>>(cnt, start, NN);
    fill_kernel<<<NE / 256, 256, 0, stream>>>(colE, start, cursor, eidx);

    // edge MLP pass A: MFMA GEMM + fused BN stats
    gemm1_mfma<0><<<NE / 64, 256, 0, stream>>>(
        x, rowE, colE, batch, edge_attr, W1p,
        nullptr, nullptr, nullptr, colsum_b, colsq_b, nullptr);
    finalize1_kernel<<<1, 256, 0, stream>>>(colsum_b, colsq_b, g1, be1, a1, b1n);

    // edge MLP pass B: recompute in CSR order, affine+relu, scatter-add
    gemm1_mfma<1><<<NE / 64, 256, 0, stream>>>(
        x, rowE, colE, batch, edge_attr, W1p,
        eidx, a1, b1n, nullptr, nullptr, agg);
    divcnt_kernel<<<(NN * LSZ / 4) / 256, 256, 0, stream>>>(agg, cnt);

    // node MLP (fp32)
    gemm2_kernel<<<dim3((NN + 63) / 64, 4), 256, 0, stream>>>(x, batch, agg, W2, Y2);
    colstats_kernel<<<(NN + 511) / 512, 256, 0, stream>>>(Y2, NN, D2, 512, colsum2, colsq2);
    finalize_kernel<<<2, 256, 0, stream>>>(colsum2, colsq2, g2, be2, a2, b2n, D2, 1.0f / NN);

    // output linear
    gemm3_kernel<<<dim3((NN + 63) / 64, 1), 256, 0, stream>>>(Y2, a2, b2n, W3, b3, out);
}

// Round 4
// 1818.534 us; speedup vs baseline: 3.2960x; 1.3501x over previous
//
#include <hip/hip_runtime.h>

#define NN 50000      // nodes
#define NE 800000     // edges
#define NF 128        // node features
#define EF 64         // edge features
#define LSZ 256       // layer size
#define D1 193        // NF+EF+1
#define D2 385        // NF+LSZ+1
#define Y2S 416       // Y2 row stride = 13*32 (gemm3 K, padded)
#define BN_EPS 1e-5f

typedef float f32x4 __attribute__((ext_vector_type(4)));
typedef short s16x8 __attribute__((ext_vector_type(8)));

__device__ __forceinline__ unsigned short f2bf(float f) {
    unsigned u = __float_as_uint(f);
    u += 0x7FFFu + ((u >> 16) & 1u);   // RNE
    return (unsigned short)(u >> 16);
}
__device__ __forceinline__ float bf2f(unsigned short s) {
    return __uint_as_float(((unsigned)s) << 16);
}

// ===========================================================================
// Generic weight pre-pack into MFMA B-fragment order.
// Fragment (s, i): k' = s*32 + (lane>>4)*8 + j ; col n = 16*i + (lane&15).
// Source row = k' (or k'+1 if k' >= batch_row, skipping the rank-1 batch row).
// Zero outside [kmax_src rows x ncols].
// ===========================================================================
__global__ void prep_w_kernel(const float* __restrict__ W, int ldw, int ncols,
                              int kmax_src, int batch_row, int nfrag, int ksteps,
                              unsigned short* __restrict__ Wp)
{
    int t = blockIdx.x * 256 + threadIdx.x;
    if (t >= ksteps * nfrag * 64) return;
    int lane = t & 63, si = t >> 6;
    int i = si % nfrag, s = si / nfrag;
    int q = lane >> 4, n = (i << 4) + (lane & 15);
    unsigned short v[8];
#pragma unroll
    for (int j = 0; j < 8; j++) {
        int k = s * 32 + q * 8 + j;
        int sr = (batch_row >= 0 && k >= batch_row) ? k + 1 : k;
        v[j] = (sr < kmax_src && n < ncols) ? f2bf(W[(size_t)sr * ldw + n])
                                            : (unsigned short)0;
    }
    *(uint4*)&Wp[(size_t)t * 8] = *(const uint4*)v;
}

// ===========================================================================
// GEMM1: block = 64 edges x 256 cols, 4 waves; wave owns 64 cols (4 N-frags).
// K = 192 (x 128 | edge_attr 64); batch column applied rank-1 in epilogue.
// MODE 0: BN stats (bucketed col sum/sumsq).  MODE 1: CSR order, BN affine +
// ReLU + run-merged scatter-add into aggsum.
// ===========================================================================
template <int MODE>
__global__ __launch_bounds__(256, 3) void gemm1_mfma(
    const float* __restrict__ x, const int* __restrict__ rowi,
    const int* __restrict__ colE, const int* __restrict__ batch,
    const float* __restrict__ ea, const float* __restrict__ W1,
    const unsigned short* __restrict__ W1p, const int* __restrict__ eidx,
    const float* __restrict__ a1, const float* __restrict__ b1n,
    float* __restrict__ colsum_b, float* __restrict__ colsq_b,
    float* __restrict__ aggsum)
{
    __shared__ int   rowS[64];
    __shared__ int   eSs[64];
    __shared__ float bvalS[64];
    __shared__ int   destS[64];

    const int tid = threadIdx.x;
    const int lane = tid & 63, wave = tid >> 6;
    const int quad = lane >> 4, l15 = lane & 15;
    const int e0 = blockIdx.x * 64;

    if (tid < 64) {
        int e = (MODE == 1) ? eidx[e0 + tid] : (e0 + tid);
        eSs[tid] = e;
        int r = rowi[e];
        rowS[tid] = r;
        bvalS[tid] = (float)batch[r];
        if (MODE == 1) destS[tid] = colE[e];
    }
    __syncthreads();

    int rE[4], eE[4];
#pragma unroll
    for (int mf = 0; mf < 4; mf++) {
        rE[mf] = rowS[mf * 16 + l15];
        eE[mf] = eSs[mf * 16 + l15];
    }

    const s16x8* Bp = (const s16x8*)W1p;
    f32x4 acc[4][4];
#pragma unroll
    for (int mf = 0; mf < 4; mf++)
#pragma unroll
        for (int f = 0; f < 4; f++) acc[mf][f] = (f32x4){0.f, 0.f, 0.f, 0.f};

#pragma unroll
    for (int s = 0; s < 6; s++) {
        s16x8 bf[4];
#pragma unroll
        for (int f = 0; f < 4; f++)
            bf[f] = Bp[(size_t)(s * 16 + wave * 4 + f) * 64 + lane];
        s16x8 af[4];
#pragma unroll
        for (int mf = 0; mf < 4; mf++) {
            const float* src = (s < 4)
                ? (x  + (size_t)rE[mf] * NF + s * 32 + quad * 8)
                : (ea + (size_t)eE[mf] * EF + (s - 4) * 32 + quad * 8);
            float4 v0 = ((const float4*)src)[0];
            float4 v1 = ((const float4*)src)[1];
            af[mf][0] = (short)f2bf(v0.x); af[mf][1] = (short)f2bf(v0.y);
            af[mf][2] = (short)f2bf(v0.z); af[mf][3] = (short)f2bf(v0.w);
            af[mf][4] = (short)f2bf(v1.x); af[mf][5] = (short)f2bf(v1.y);
            af[mf][6] = (short)f2bf(v1.z); af[mf][7] = (short)f2bf(v1.w);
        }
#pragma unroll
        for (int mf = 0; mf < 4; mf++)
#pragma unroll
            for (int f = 0; f < 4; f++)
                acc[mf][f] = __builtin_amdgcn_mfma_f32_16x16x32_bf16(
                    af[mf], bf[f], acc[mf][f], 0, 0, 0);
    }

    // C/D: element r of lane = C[row = mf*16 + quad*4 + r][col = 16*i + l15]
    float bv[4][4];
#pragma unroll
    for (int mf = 0; mf < 4; mf++)
#pragma unroll
        for (int r = 0; r < 4; r++) bv[mf][r] = bvalS[mf * 16 + quad * 4 + r];

    if (MODE == 0) {
        const int bucket = blockIdx.x & 63;
#pragma unroll
        for (int f = 0; f < 4; f++) {
            const int col = ((wave * 4 + f) << 4) + l15;
            const float w1b = W1[(size_t)128 * LSZ + col];   // rank-1 batch row
            float s = 0.f, q = 0.f;
#pragma unroll
            for (int mf = 0; mf < 4; mf++)
#pragma unroll
                for (int r = 0; r < 4; r++) {
                    float y = fmaf(bv[mf][r], w1b, acc[mf][f][r]);
                    s += y; q += y * y;
                }
            s += __shfl_xor(s, 16); s += __shfl_xor(s, 32);
            q += __shfl_xor(q, 16); q += __shfl_xor(q, 32);
            if (quad == 0) {
                atomicAdd(&colsum_b[bucket * LSZ + col], s);
                atomicAdd(&colsq_b [bucket * LSZ + col], q);
            }
        }
    } else {
        int dd[4][4];
#pragma unroll
        for (int mf = 0; mf < 4; mf++)
#pragma unroll
            for (int r = 0; r < 4; r++) dd[mf][r] = destS[mf * 16 + quad * 4 + r];
#pragma unroll
        for (int f = 0; f < 4; f++) {
            const int col = ((wave * 4 + f) << 4) + l15;
            const float w1b = W1[(size_t)128 * LSZ + col];
            const float Ac = a1[col], Bc = b1n[col];
#pragma unroll
            for (int mf = 0; mf < 4; mf++) {
                int cur = dd[mf][0];
                float run = fmaxf(fmaf(fmaf(bv[mf][0], w1b, acc[mf][f][0]), Ac, Bc), 0.f);
#pragma unroll
                for (int r = 1; r < 4; r++) {
                    float y = fmaxf(fmaf(fmaf(bv[mf][r], w1b, acc[mf][f][r]), Ac, Bc), 0.f);
                    if (dd[mf][r] != cur) {
                        atomicAdd(&aggsum[(size_t)cur * LSZ + col], run);
                        cur = dd[mf][r]; run = y;
                    } else run += y;
                }
                atomicAdd(&aggsum[(size_t)cur * LSZ + col], run);
            }
        }
    }
}

// ---------------------------------------------------------------------------
// finalize layer-1 BN: reduce 64 buckets, fold gamma/beta into affine a,b
// ---------------------------------------------------------------------------
__global__ void finalize1_kernel(
    const float* __restrict__ colsum_b, const float* __restrict__ colsq_b,
    const float* __restrict__ gamma, const float* __restrict__ beta,
    float* __restrict__ a, float* __restrict__ b)
{
    int c = threadIdx.x;  // 256
    float s = 0.f, q = 0.f;
    for (int bk = 0; bk < 64; bk++) {
        s += colsum_b[bk * LSZ + c];
        q += colsq_b [bk * LSZ + c];
    }
    float mu  = s * (1.0f / NE);
    float var = fmaxf(q * (1.0f / NE) - mu * mu, 0.f);
    float sc  = gamma[c] * rsqrtf(var + BN_EPS);
    a[c] = sc;
    b[c] = beta[c] - mu * sc;
}

// ---------------------------------------------------------------------------
// CSR build: histogram, single-block scan, slot fill
// ---------------------------------------------------------------------------
__global__ void hist_kernel(const int* __restrict__ colE, int* __restrict__ cnt)
{
    int e = blockIdx.x * 256 + threadIdx.x;
    if (e < NE) atomicAdd(&cnt[colE[e]], 1);
}

__global__ __launch_bounds__(1024) void scan_kernel(
    const int* __restrict__ cnt, int* __restrict__ start, int n)
{
    __shared__ int wsum[16];
    __shared__ int carry_s;
    int tid = threadIdx.x;
    if (tid == 0) { carry_s = 0; start[0] = 0; }
    __syncthreads();
    for (int base = 0; base < n; base += 1024) {
        int i = base + tid;
        int v = (i < n) ? cnt[i] : 0;
        int lane = tid & 63, wave = tid >> 6;
        int sv = v;
#pragma unroll
        for (int off = 1; off < 64; off <<= 1) {
            int t = __shfl_up(sv, off);
            if (lane >= off) sv += t;
        }
        __syncthreads();
        if (lane == 63) wsum[wave] = sv;
        __syncthreads();
        int carry = carry_s;
        int woff = carry;
        for (int w = 0; w < wave; w++) woff += wsum[w];
        int incl = sv + woff;
        if (i < n) start[i + 1] = incl;
        int total = carry;
#pragma unroll
        for (int w = 0; w < 16; w++) total += wsum[w];
        __syncthreads();
        if (tid == 0) carry_s = total;
    }
}

__global__ void fill_kernel(const int* __restrict__ colE, const int* __restrict__ start,
                            int* __restrict__ cursor, int* __restrict__ eidx)
{
    int e = blockIdx.x * 256 + threadIdx.x;
    if (e < NE) {
        int c = colE[e];
        int p = start[c] + atomicAdd(&cursor[c], 1);
        eidx[p] = e;
    }
}

// ---------------------------------------------------------------------------
// agg[n,c] = aggsum[n,c] / max(cnt[n],1)   (in-place, float4)
// ---------------------------------------------------------------------------
__global__ __launch_bounds__(256) void divcnt_kernel(
    float* __restrict__ agg, const int* __restrict__ cnt)
{
    int f = blockIdx.x * 256 + threadIdx.x;
    int n = f >> 6;                       // 64 float4 per 256-col row
    if (n < NN) {
        float inv = 1.0f / fmaxf((float)cnt[n], 1.0f);
        float4* p = (float4*)agg + f;
        float4 v = *p;
        v.x *= inv; v.y *= inv; v.z *= inv; v.w *= inv;
        *p = v;
    }
}

// ===========================================================================
// GEMM2 (MFMA): Y2[n,c] = h2[n,:]·W2[:,c], batch column rank-1 in epilogue.
// K = 384 (x 128 | agg 256). N padded to 416 (26 frags); grid.y in {0,1}
// covers 16 frags each (mask i>=26). Y2 stored bf16 with stride 416.
// ===========================================================================
__global__ __launch_bounds__(256, 3) void gemm2_mfma(
    const float* __restrict__ x, const int* __restrict__ batch,
    const float* __restrict__ agg, const float* __restrict__ W2,
    const unsigned short* __restrict__ W2p, unsigned short* __restrict__ Y2)
{
    __shared__ float bvalS[64];
    const int tid = threadIdx.x;
    const int lane = tid & 63, wave = tid >> 6;
    const int quad = lane >> 4, l15 = lane & 15;
    const int n0 = blockIdx.x * 64;
    const int fbase = blockIdx.y * 16 + wave * 4;

    if (tid < 64) bvalS[tid] = (float)batch[min(n0 + tid, NN - 1)];
    __syncthreads();

    int rn[4];
#pragma unroll
    for (int mf = 0; mf < 4; mf++) rn[mf] = min(n0 + mf * 16 + l15, NN - 1);

    const s16x8* Bp = (const s16x8*)W2p;
    f32x4 acc[4][4];
#pragma unroll
    for (int mf = 0; mf < 4; mf++)
#pragma unroll
        for (int f = 0; f < 4; f++) acc[mf][f] = (f32x4){0.f, 0.f, 0.f, 0.f};

#pragma unroll
    for (int s = 0; s < 12; s++) {
        s16x8 bf[4];
#pragma unroll
        for (int f = 0; f < 4; f++)
            if (fbase + f < 26)
                bf[f] = Bp[(size_t)(s * 26 + fbase + f) * 64 + lane];
        s16x8 af[4];
#pragma unroll
        for (int mf = 0; mf < 4; mf++) {
            const float* src = (s < 4)
                ? (x   + (size_t)rn[mf] * NF  + s * 32 + quad * 8)
                : (agg + (size_t)rn[mf] * LSZ + (s - 4) * 32 + quad * 8);
            float4 v0 = ((const float4*)src)[0];
            float4 v1 = ((const float4*)src)[1];
            af[mf][0] = (short)f2bf(v0.x); af[mf][1] = (short)f2bf(v0.y);
            af[mf][2] = (short)f2bf(v0.z); af[mf][3] = (short)f2bf(v0.w);
            af[mf][4] = (short)f2bf(v1.x); af[mf][5] = (short)f2bf(v1.y);
            af[mf][6] = (short)f2bf(v1.z); af[mf][7] = (short)f2bf(v1.w);
        }
#pragma unroll
        for (int mf = 0; mf < 4; mf++)
#pragma unroll
            for (int f = 0; f < 4; f++)
                if (fbase + f < 26)
                    acc[mf][f] = __builtin_amdgcn_mfma_f32_16x16x32_bf16(
                        af[mf], bf[f], acc[mf][f], 0, 0, 0);
    }

    float bv[4][4];
#pragma unroll
    for (int mf = 0; mf < 4; mf++)
#pragma unroll
        for (int r = 0; r < 4; r++) bv[mf][r] = bvalS[mf * 16 + quad * 4 + r];

#pragma unroll
    for (int f = 0; f < 4; f++) {
        int i = fbase + f;
        if (i < 26) {
            const int col = (i << 4) + l15;
            const float w2b = (col < D2) ? W2[(size_t)128 * D2 + col] : 0.f;
#pragma unroll
            for (int mf = 0; mf < 4; mf++)
#pragma unroll
                for (int r = 0; r < 4; r++) {
                    int n = n0 + mf * 16 + quad * 4 + r;
                    if (n < NN)
                        Y2[(size_t)n * Y2S + col] =
                            f2bf(fmaf(bv[mf][r], w2b, acc[mf][f][r]));
                }
        }
    }
}

// ---------------------------------------------------------------------------
// Column sum / sumsq over bf16 [rows x cols] matrix with row stride
// ---------------------------------------------------------------------------
__global__ __launch_bounds__(256) void colstats_bf16_kernel(
    const unsigned short* __restrict__ Y, int rows, int cols, int stride,
    int rows_per_block, float* __restrict__ sum, float* __restrict__ sumsq)
{
    int r0 = blockIdx.x * rows_per_block;
    int r1 = min(r0 + rows_per_block, rows);
    for (int c = threadIdx.x; c < cols; c += 256) {
        float s = 0.f, s2 = 0.f;
        for (int r = r0; r < r1; r++) {
            float v = bf2f(Y[(size_t)r * stride + c]);
            s += v; s2 += v * v;
        }
        atomicAdd(&sum[c], s);
        atomicAdd(&sumsq[c], s2);
    }
}

__global__ void finalize_kernel(
    const float* __restrict__ sum, const float* __restrict__ sumsq,
    const float* __restrict__ gamma, const float* __restrict__ beta,
    float* __restrict__ a, float* __restrict__ b, int cols, float invn)
{
    int c = blockIdx.x * blockDim.x + threadIdx.x;
    if (c < cols) {
        float mu  = sum[c] * invn;
        float var = fmaxf(sumsq[c] * invn - mu * mu, 0.f);
        float s   = gamma[c] * rsqrtf(var + BN_EPS);
        a[c] = s;
        b[c] = beta[c] - mu * s;
    }
}

// ===========================================================================
// GEMM3 (MFMA): out[n,c] = relu( relu(a2⊙Y2[n,:]+b2n)·W3[:,c] + b3[c] )
// K = 416 (13 steps, pads have a2=b2n=0 -> A=0). N = 128 = 8 frags,
// 4 waves x 2 frags. BN affine + ReLU fused into the A build.
// ===========================================================================
__global__ __launch_bounds__(256, 3) void gemm3_mfma(
    const unsigned short* __restrict__ Y2, const float* __restrict__ a2,
    const float* __restrict__ b2n, const unsigned short* __restrict__ W3p,
    const float* __restrict__ b3, float* __restrict__ out)
{
    const int tid = threadIdx.x;
    const int lane = tid & 63, wave = tid >> 6;
    const int quad = lane >> 4, l15 = lane & 15;
    const int n0 = blockIdx.x * 64;

    int rn[4];
#pragma unroll
    for (int mf = 0; mf < 4; mf++) rn[mf] = min(n0 + mf * 16 + l15, NN - 1);

    const s16x8* Bp = (const s16x8*)W3p;
    f32x4 acc[4][2];
#pragma unroll
    for (int mf = 0; mf < 4; mf++)
#pragma unroll
        for (int f = 0; f < 2; f++) acc[mf][f] = (f32x4){0.f, 0.f, 0.f, 0.f};

#pragma unroll
    for (int s = 0; s < 13; s++) {
        const int kb = s * 32 + quad * 8;
        float4 A0 = *(const float4*)&a2[kb],  A1 = *(const float4*)&a2[kb + 4];
        float4 B0 = *(const float4*)&b2n[kb], B1 = *(const float4*)&b2n[kb + 4];
        float Aj[8] = {A0.x, A0.y, A0.z, A0.w, A1.x, A1.y, A1.z, A1.w};
        float Bj[8] = {B0.x, B0.y, B0.z, B0.w, B1.x, B1.y, B1.z, B1.w};
        s16x8 bf[2];
#pragma unroll
        for (int f = 0; f < 2; f++)
            bf[f] = Bp[(size_t)(s * 8 + wave * 2 + f) * 64 + lane];
#pragma unroll
        for (int mf = 0; mf < 4; mf++) {
            s16x8 yv = *(const s16x8*)&Y2[(size_t)rn[mf] * Y2S + kb];
            s16x8 af;
#pragma unroll
            for (int j = 0; j < 8; j++) {
                float y = bf2f((unsigned short)yv[j]);
                y = fmaxf(fmaf(y, Aj[j], Bj[j]), 0.f);
                af[j] = (short)f2bf(y);
            }
#pragma unroll
            for (int f = 0; f < 2; f++)
                acc[mf][f] = __builtin_amdgcn_mfma_f32_16x16x32_bf16(
                    af, bf[f], acc[mf][f], 0, 0, 0);
        }
    }

#pragma unroll
    for (int f = 0; f < 2; f++) {
        const int col = ((wave * 2 + f) << 4) + l15;
        const float bb = b3[col];
#pragma unroll
        for (int mf = 0; mf < 4; mf++)
#pragma unroll
            for (int r = 0; r < 4; r++) {
                int n = n0 + mf * 16 + quad * 4 + r;
                if (n < NN)
                    out[(size_t)n * NF + col] = fmaxf(acc[mf][f][r] + bb, 0.f);
            }
    }
}

// ---------------------------------------------------------------------------
extern "C" void kernel_launch(void* const* d_in, const int* in_sizes, int n_in,
                              void* d_out, int out_size, void* d_ws, size_t ws_size,
                              hipStream_t stream)
{
    const float* x         = (const float*)d_in[0];
    const int*   edge_idx  = (const int*)d_in[1];
    const float* edge_attr = (const float*)d_in[2];
    // d_in[3] = u : unused by the reference
    const int*   batch     = (const int*)d_in[4];
    const float* W1        = (const float*)d_in[5];
    // d_in[6] = b1 : cancelled by BatchNorm
    const float* g1        = (const float*)d_in[7];
    const float* be1       = (const float*)d_in[8];
    const float* W2        = (const float*)d_in[9];
    // d_in[10] = b2 : cancelled by BatchNorm
    const float* g2        = (const float*)d_in[11];
    const float* be2       = (const float*)d_in[12];
    const float* W3        = (const float*)d_in[13];
    const float* b3        = (const float*)d_in[14];
    float* out = (float*)d_out;

    const int* rowE = edge_idx;        // edge_index[0]
    const int* colE = edge_idx + NE;   // edge_index[1]

    // ---- workspace layout (~97.3 MB) ----
    char* ws = (char*)d_ws;
    size_t off = 0;
    auto alloc = [&](size_t bytes) -> void* {
        void* p = ws + off;
        off += (bytes + 255) & ~(size_t)255;
        return p;
    };
    unsigned short* Y2   = (unsigned short*)alloc((size_t)NN * Y2S * 2);  // 41.6 MB
    int*            eidx = (int*)alloc((size_t)NE * 4);                   //  3.2 MB
    int*            start= (int*)alloc((size_t)(NN + 1) * 4);
    float*          a1   = (float*)alloc(LSZ * 4);
    float*          b1n  = (float*)alloc(LSZ * 4);
    unsigned short* W1p  = (unsigned short*)alloc((size_t)6  * 16 * 64 * 8 * 2); //  96 KB
    unsigned short* W2p  = (unsigned short*)alloc((size_t)12 * 26 * 64 * 8 * 2); // 312 KB
    unsigned short* W3p  = (unsigned short*)alloc((size_t)13 * 8  * 64 * 8 * 2); // 104 KB
    size_t zoff = off;                                             // ---- zero region ----
    float* agg      = (float*)alloc((size_t)NN * LSZ * 4);         // 51.2 MB
    int*   cnt      = (int*)  alloc((size_t)NN * 4);
    int*   cursor   = (int*)  alloc((size_t)NN * 4);
    float* colsum_b = (float*)alloc(64 * LSZ * 4);
    float* colsq_b  = (float*)alloc(64 * LSZ * 4);
    float* colsum2  = (float*)alloc(Y2S * 4);
    float* colsq2   = (float*)alloc(Y2S * 4);
    float* a2       = (float*)alloc(Y2S * 4);   // pads (>=385) must stay 0
    float* b2n      = (float*)alloc(Y2S * 4);
    size_t total = off;
    if (ws_size < total) return;

    hipMemsetAsync(ws + zoff, 0, total - zoff, stream);

    // weight pre-pack into fragment order (rank-1 batch row skipped for W1/W2)
    prep_w_kernel<<<(6  * 16 * 64 + 255) / 256, 256, 0, stream>>>(W1, LSZ, LSZ, D1, 128, 16, 6,  W1p);
    prep_w_kernel<<<(12 * 26 * 64 + 255) / 256, 256, 0, stream>>>(W2, D2,  D2,  D2, 128, 26, 12, W2p);
    prep_w_kernel<<<(13 * 8  * 64 + 255) / 256, 256, 0, stream>>>(W3, NF,  NF,  D2, -1,  8,  13, W3p);

    // CSR by destination node
    hist_kernel<<<NE / 256, 256, 0, stream>>>(colE, cnt);
    scan_kernel<<<1, 1024, 0, stream>>>(cnt, start, NN);
    fill_kernel<<<NE / 256, 256, 0, stream>>>(colE, start, cursor, eidx);

    // edge MLP pass A: MFMA GEMM + fused BN stats
    gemm1_mfma<0><<<NE / 64, 256, 0, stream>>>(
        x, rowE, colE, batch, edge_attr, W1, W1p,
        nullptr, nullptr, nullptr, colsum_b, colsq_b, nullptr);
    finalize1_kernel<<<1, 256, 0, stream>>>(colsum_b, colsq_b, g1, be1, a1, b1n);

    // edge MLP pass B: recompute in CSR order, affine+relu, scatter-add
    gemm1_mfma<1><<<NE / 64, 256, 0, stream>>>(
        x, rowE, colE, batch, edge_attr, W1, W1p,
        eidx, a1, b1n, nullptr, nullptr, agg);
    divcnt_kernel<<<(NN * LSZ / 4) / 256, 256, 0, stream>>>(agg, cnt);

    // node MLP (MFMA, bf16 Y2)
    gemm2_mfma<<<dim3((NN + 63) / 64, 2), 256, 0, stream>>>(x, batch, agg, W2, W2p, Y2);
    colstats_bf16_kernel<<<(NN + 511) / 512, 256, 0, stream>>>(Y2, NN, D2, Y2S, 512, colsum2, colsq2);
    finalize_kernel<<<2, 256, 0, stream>>>(colsum2, colsq2, g2, be2, a2, b2n, D2, 1.0f / NN);

    // output linear (MFMA, BN affine + ReLU fused into A build)
    gemm3_mfma<<<(NN + 63) / 64, 256, 0, stream>>>(Y2, a2, b2n, W3p, b3, out);
}

// Round 5
// 1299.335 us; speedup vs baseline: 4.6130x; 1.3996x over previous
//
#include <hip/hip_runtime.h>

#define NN 50000      // nodes
#define NE 800000     // edges
#define NF 128        // node features
#define EF 64         // edge features
#define LSZ 256       // layer size
#define D1 193        // NF+EF+1
#define D2 385        // NF+LSZ+1
#define Y2S 416       // Y2 row stride = 13*32 (gemm3 K, padded)
#define ALD 208       // gemm1 LDS A row stride (bf16 elems)
#define BN_EPS 1e-5f

typedef float f32x4 __attribute__((ext_vector_type(4)));
typedef short s16x8 __attribute__((ext_vector_type(8)));

__device__ __forceinline__ unsigned short f2bf(float f) {
    unsigned u = __float_as_uint(f);
    u += 0x7FFFu + ((u >> 16) & 1u);   // RNE
    return (unsigned short)(u >> 16);
}
__device__ __forceinline__ float bf2f(unsigned short s) {
    return __uint_as_float(((unsigned)s) << 16);
}

// ===========================================================================
// Generic weight pre-pack into MFMA B-fragment order.
// Fragment (s, i): k' = s*32 + (lane>>4)*8 + j ; col n = 16*i + (lane&15).
// Source row = k' (or k'+1 if k' >= batch_row, skipping the rank-1 batch row).
// ===========================================================================
__global__ void prep_w_kernel(const float* __restrict__ W, int ldw, int ncols,
                              int kmax_src, int batch_row, int nfrag, int ksteps,
                              unsigned short* __restrict__ Wp)
{
    int t = blockIdx.x * 256 + threadIdx.x;
    if (t >= ksteps * nfrag * 64) return;
    int lane = t & 63, si = t >> 6;
    int i = si % nfrag, s = si / nfrag;
    int q = lane >> 4, n = (i << 4) + (lane & 15);
    unsigned short v[8];
#pragma unroll
    for (int j = 0; j < 8; j++) {
        int k = s * 32 + q * 8 + j;
        int sr = (batch_row >= 0 && k >= batch_row) ? k + 1 : k;
        v[j] = (sr < kmax_src && n < ncols) ? f2bf(W[(size_t)sr * ldw + n])
                                            : (unsigned short)0;
    }
    *(uint4*)&Wp[(size_t)t * 8] = *(const uint4*)v;
}

// ===========================================================================
// GEMM1: block = 64 edges x 256 cols, 4 waves; wave owns 64 cols (4 N-frags).
// K = 192; batch column applied rank-1 in epilogue.
// A staged through LDS with coalesced row bursts (bf16), B double-buffered.
// MODE 0: BN stats (bucketed col sum/sumsq).  MODE 1: CSR order, BN affine +
// ReLU + run-merged scatter-add into aggsum.
// ===========================================================================
template <int MODE>
__global__ __launch_bounds__(256, 3) void gemm1_mfma(
    const float* __restrict__ x, const int* __restrict__ rowi,
    const int* __restrict__ colE, const int* __restrict__ batch,
    const float* __restrict__ ea, const float* __restrict__ W1,
    const unsigned short* __restrict__ W1p, const int* __restrict__ eidx,
    const float* __restrict__ a1, const float* __restrict__ b1n,
    float* __restrict__ colsum_b, float* __restrict__ colsq_b,
    float* __restrict__ aggsum)
{
    __shared__ unsigned short Asm[64 * ALD];   // 26.6 KB, rows=edges, cols=k
    __shared__ int   rowS[64];
    __shared__ int   eSs[64];
    __shared__ float bvalS[64];
    __shared__ int   destS[64];

    const int tid = threadIdx.x;
    const int lane = tid & 63, wave = tid >> 6;
    const int quad = lane >> 4, l15 = lane & 15;
    const int e0 = blockIdx.x * 64;

    if (tid < 64) {
        int e = (MODE == 1) ? eidx[e0 + tid] : (e0 + tid);
        eSs[tid] = e;
        int r = rowi[e];
        rowS[tid] = r;
        bvalS[tid] = (float)batch[r];
        if (MODE == 1) destS[tid] = colE[e];
    }
    __syncthreads();

    // ---- stage A into LDS: x = 2048 float4 (cols 0..127), ea = 1024 float4
    // (cols 128..191). Consecutive lanes -> consecutive cols of the same row:
    // full 512B/256B row bursts. 12 independent loads/thread, one wait.
#pragma unroll
    for (int i = 0; i < 12; i++) {
        int idx = i * 256 + tid;
        int row, col4;
        const float* src;
        if (idx < 2048) {                       // compile-time resolvable per i
            row = idx >> 5; col4 = idx & 31;
            src = x + (size_t)rowS[row] * NF + col4 * 4;
        } else {
            int j = idx - 2048;
            row = j >> 4; col4 = 32 + (j & 15);
            src = ea + (size_t)eSs[row] * EF + (col4 - 32) * 4;
        }
        float4 v = *(const float4*)src;
        ushort4 h;
        h.x = f2bf(v.x); h.y = f2bf(v.y); h.z = f2bf(v.z); h.w = f2bf(v.w);
        *(uint2*)&Asm[row * ALD + col4 * 4] = *(uint2*)&h;
    }
    __syncthreads();

    const s16x8* Bp = (const s16x8*)W1p;
    f32x4 acc[4][4];
#pragma unroll
    for (int mf = 0; mf < 4; mf++)
#pragma unroll
        for (int f = 0; f < 4; f++) acc[mf][f] = (f32x4){0.f, 0.f, 0.f, 0.f};

    s16x8 bcur[4], bnxt[4];
#pragma unroll
    for (int f = 0; f < 4; f++)
        bcur[f] = Bp[(size_t)(wave * 4 + f) * 64 + lane];

#pragma unroll
    for (int s = 0; s < 6; s++) {
        if (s < 5) {
#pragma unroll
            for (int f = 0; f < 4; f++)
                bnxt[f] = Bp[(size_t)((s + 1) * 16 + wave * 4 + f) * 64 + lane];
        }
        s16x8 af[4];
#pragma unroll
        for (int mf = 0; mf < 4; mf++)
            af[mf] = *(const s16x8*)&Asm[(mf * 16 + l15) * ALD + s * 32 + quad * 8];
#pragma unroll
        for (int mf = 0; mf < 4; mf++)
#pragma unroll
            for (int f = 0; f < 4; f++)
                acc[mf][f] = __builtin_amdgcn_mfma_f32_16x16x32_bf16(
                    af[mf], bcur[f], acc[mf][f], 0, 0, 0);
#pragma unroll
        for (int f = 0; f < 4; f++) bcur[f] = bnxt[f];
    }

    // C/D: element r of lane = C[row = mf*16 + quad*4 + r][col = 16*i + l15]
    float bv[4][4];
#pragma unroll
    for (int mf = 0; mf < 4; mf++)
#pragma unroll
        for (int r = 0; r < 4; r++) bv[mf][r] = bvalS[mf * 16 + quad * 4 + r];

    if (MODE == 0) {
        const int bucket = blockIdx.x & 63;
#pragma unroll
        for (int f = 0; f < 4; f++) {
            const int col = ((wave * 4 + f) << 4) + l15;
            const float w1b = W1[(size_t)128 * LSZ + col];   // rank-1 batch row
            float s = 0.f, q = 0.f;
#pragma unroll
            for (int mf = 0; mf < 4; mf++)
#pragma unroll
                for (int r = 0; r < 4; r++) {
                    float y = fmaf(bv[mf][r], w1b, acc[mf][f][r]);
                    s += y; q += y * y;
                }
            s += __shfl_xor(s, 16); s += __shfl_xor(s, 32);
            q += __shfl_xor(q, 16); q += __shfl_xor(q, 32);
            if (quad == 0) {
                atomicAdd(&colsum_b[bucket * LSZ + col], s);
                atomicAdd(&colsq_b [bucket * LSZ + col], q);
            }
        }
    } else {
        int dd[4][4];
#pragma unroll
        for (int mf = 0; mf < 4; mf++)
#pragma unroll
            for (int r = 0; r < 4; r++) dd[mf][r] = destS[mf * 16 + quad * 4 + r];
#pragma unroll
        for (int f = 0; f < 4; f++) {
            const int col = ((wave * 4 + f) << 4) + l15;
            const float w1b = W1[(size_t)128 * LSZ + col];
            const float Ac = a1[col], Bc = b1n[col];
#pragma unroll
            for (int mf = 0; mf < 4; mf++) {
                int cur = dd[mf][0];
                float run = fmaxf(fmaf(fmaf(bv[mf][0], w1b, acc[mf][f][0]), Ac, Bc), 0.f);
#pragma unroll
                for (int r = 1; r < 4; r++) {
                    float y = fmaxf(fmaf(fmaf(bv[mf][r], w1b, acc[mf][f][r]), Ac, Bc), 0.f);
                    if (dd[mf][r] != cur) {
                        atomicAdd(&aggsum[(size_t)cur * LSZ + col], run);
                        cur = dd[mf][r]; run = y;
                    } else run += y;
                }
                atomicAdd(&aggsum[(size_t)cur * LSZ + col], run);
            }
        }
    }
}

// ---------------------------------------------------------------------------
// finalize layer-1 BN: reduce 64 buckets, fold gamma/beta into affine a,b
// ---------------------------------------------------------------------------
__global__ void finalize1_kernel(
    const float* __restrict__ colsum_b, const float* __restrict__ colsq_b,
    const float* __restrict__ gamma, const float* __restrict__ beta,
    float* __restrict__ a, float* __restrict__ b)
{
    int c = threadIdx.x;  // 256
    float s = 0.f, q = 0.f;
    for (int bk = 0; bk < 64; bk++) {
        s += colsum_b[bk * LSZ + c];
        q += colsq_b [bk * LSZ + c];
    }
    float mu  = s * (1.0f / NE);
    float var = fmaxf(q * (1.0f / NE) - mu * mu, 0.f);
    float sc  = gamma[c] * rsqrtf(var + BN_EPS);
    a[c] = sc;
    b[c] = beta[c] - mu * sc;
}

// ---------------------------------------------------------------------------
// finalize layer-2 BN: reduce 64 buckets (stride Y2S), affine a2,b2n
// ---------------------------------------------------------------------------
__global__ void finalize2_kernel(
    const float* __restrict__ colsum_b, const float* __restrict__ colsq_b,
    const float* __restrict__ gamma, const float* __restrict__ beta,
    float* __restrict__ a, float* __restrict__ b)
{
    int c = blockIdx.x * 256 + threadIdx.x;
    if (c >= D2) return;
    float s = 0.f, q = 0.f;
    for (int bk = 0; bk < 64; bk++) {
        s += colsum_b[bk * Y2S + c];
        q += colsq_b [bk * Y2S + c];
    }
    float mu  = s * (1.0f / NN);
    float var = fmaxf(q * (1.0f / NN) - mu * mu, 0.f);
    float sc  = gamma[c] * rsqrtf(var + BN_EPS);
    a[c] = sc;
    b[c] = beta[c] - mu * sc;
}

// ---------------------------------------------------------------------------
// CSR build: histogram, single-block scan, slot fill
// ---------------------------------------------------------------------------
__global__ void hist_kernel(const int* __restrict__ colE, int* __restrict__ cnt)
{
    int e = blockIdx.x * 256 + threadIdx.x;
    if (e < NE) atomicAdd(&cnt[colE[e]], 1);
}

__global__ __launch_bounds__(1024) void scan_kernel(
    const int* __restrict__ cnt, int* __restrict__ start, int n)
{
    __shared__ int wsum[16];
    __shared__ int carry_s;
    int tid = threadIdx.x;
    if (tid == 0) { carry_s = 0; start[0] = 0; }
    __syncthreads();
    for (int base = 0; base < n; base += 1024) {
        int i = base + tid;
        int v = (i < n) ? cnt[i] : 0;
        int lane = tid & 63, wave = tid >> 6;
        int sv = v;
#pragma unroll
        for (int off = 1; off < 64; off <<= 1) {
            int t = __shfl_up(sv, off);
            if (lane >= off) sv += t;
        }
        __syncthreads();
        if (lane == 63) wsum[wave] = sv;
        __syncthreads();
        int carry = carry_s;
        int woff = carry;
        for (int w = 0; w < wave; w++) woff += wsum[w];
        int incl = sv + woff;
        if (i < n) start[i + 1] = incl;
        int total = carry;
#pragma unroll
        for (int w = 0; w < 16; w++) total += wsum[w];
        __syncthreads();
        if (tid == 0) carry_s = total;
    }
}

__global__ void fill_kernel(const int* __restrict__ colE, const int* __restrict__ start,
                            int* __restrict__ cursor, int* __restrict__ eidx)
{
    int e = blockIdx.x * 256 + threadIdx.x;
    if (e < NE) {
        int c = colE[e];
        int p = start[c] + atomicAdd(&cursor[c], 1);
        eidx[p] = e;
    }
}

// ---------------------------------------------------------------------------
// agg[n,c] = aggsum[n,c] / max(cnt[n],1)   (in-place, float4)
// ---------------------------------------------------------------------------
__global__ __launch_bounds__(256) void divcnt_kernel(
    float* __restrict__ agg, const int* __restrict__ cnt)
{
    int f = blockIdx.x * 256 + threadIdx.x;
    int n = f >> 6;                       // 64 float4 per 256-col row
    if (n < NN) {
        float inv = 1.0f / fmaxf((float)cnt[n], 1.0f);
        float4* p = (float4*)agg + f;
        float4 v = *p;
        v.x *= inv; v.y *= inv; v.z *= inv; v.w *= inv;
        *p = v;
    }
}

// ===========================================================================
// GEMM2 (MFMA): Y2[n,c] = h2[n,:]·W2[:,c], batch rank-1 in epilogue,
// BN stats fused (bucketed col sum/sumsq). K = 384 (x 128 | agg 256).
// N padded to 416 (26 frags); grid.y in {0,1}. Y2 stored bf16, stride 416.
// ===========================================================================
__global__ __launch_bounds__(256, 3) void gemm2_mfma(
    const float* __restrict__ x, const int* __restrict__ batch,
    const float* __restrict__ agg, const float* __restrict__ W2,
    const unsigned short* __restrict__ W2p, unsigned short* __restrict__ Y2,
    float* __restrict__ colsum2_b, float* __restrict__ colsq2_b)
{
    __shared__ float bvalS[64];
    const int tid = threadIdx.x;
    const int lane = tid & 63, wave = tid >> 6;
    const int quad = lane >> 4, l15 = lane & 15;
    const int n0 = blockIdx.x * 64;
    const int fbase = blockIdx.y * 16 + wave * 4;

    if (tid < 64) bvalS[tid] = (float)batch[min(n0 + tid, NN - 1)];
    __syncthreads();

    int rn[4];
#pragma unroll
    for (int mf = 0; mf < 4; mf++) rn[mf] = min(n0 + mf * 16 + l15, NN - 1);

    const s16x8* Bp = (const s16x8*)W2p;
    f32x4 acc[4][4];
#pragma unroll
    for (int mf = 0; mf < 4; mf++)
#pragma unroll
        for (int f = 0; f < 4; f++) acc[mf][f] = (f32x4){0.f, 0.f, 0.f, 0.f};

    s16x8 bcur[4], bnxt[4];
#pragma unroll
    for (int f = 0; f < 4; f++)
        if (fbase + f < 26) bcur[f] = Bp[(size_t)(fbase + f) * 64 + lane];

#pragma unroll
    for (int s = 0; s < 12; s++) {
        if (s < 11) {
#pragma unroll
            for (int f = 0; f < 4; f++)
                if (fbase + f < 26)
                    bnxt[f] = Bp[(size_t)((s + 1) * 26 + fbase + f) * 64 + lane];
        }
        s16x8 af[4];
#pragma unroll
        for (int mf = 0; mf < 4; mf++) {
            const float* src = (s < 4)
                ? (x   + (size_t)rn[mf] * NF  + s * 32 + quad * 8)
                : (agg + (size_t)rn[mf] * LSZ + (s - 4) * 32 + quad * 8);
            float4 v0 = ((const float4*)src)[0];
            float4 v1 = ((const float4*)src)[1];
            af[mf][0] = (short)f2bf(v0.x); af[mf][1] = (short)f2bf(v0.y);
            af[mf][2] = (short)f2bf(v0.z); af[mf][3] = (short)f2bf(v0.w);
            af[mf][4] = (short)f2bf(v1.x); af[mf][5] = (short)f2bf(v1.y);
            af[mf][6] = (short)f2bf(v1.z); af[mf][7] = (short)f2bf(v1.w);
        }
#pragma unroll
        for (int mf = 0; mf < 4; mf++)
#pragma unroll
            for (int f = 0; f < 4; f++)
                if (fbase + f < 26)
                    acc[mf][f] = __builtin_amdgcn_mfma_f32_16x16x32_bf16(
                        af[mf], bcur[f], acc[mf][f], 0, 0, 0);
#pragma unroll
        for (int f = 0; f < 4; f++) bcur[f] = bnxt[f];
    }

    float bv[4][4];
#pragma unroll
    for (int mf = 0; mf < 4; mf++)
#pragma unroll
        for (int r = 0; r < 4; r++) bv[mf][r] = bvalS[mf * 16 + quad * 4 + r];

    const int bucket = blockIdx.x & 63;
#pragma unroll
    for (int f = 0; f < 4; f++) {
        int i = fbase + f;
        if (i < 26) {
            const int col = (i << 4) + l15;
            const float w2b = (col < D2) ? W2[(size_t)128 * D2 + col] : 0.f;
            float s = 0.f, q = 0.f;
#pragma unroll
            for (int mf = 0; mf < 4; mf++)
#pragma unroll
                for (int r = 0; r < 4; r++) {
                    int n = n0 + mf * 16 + quad * 4 + r;
                    if (n < NN) {
                        float y = fmaf(bv[mf][r], w2b, acc[mf][f][r]);
                        Y2[(size_t)n * Y2S + col] = f2bf(y);
                        s += y; q += y * y;
                    }
                }
            s += __shfl_xor(s, 16); s += __shfl_xor(s, 32);
            q += __shfl_xor(q, 16); q += __shfl_xor(q, 32);
            if (quad == 0) {
                atomicAdd(&colsum2_b[bucket * Y2S + col], s);
                atomicAdd(&colsq2_b [bucket * Y2S + col], q);
            }
        }
    }
}

// ===========================================================================
// GEMM3 (MFMA): out[n,c] = relu( relu(a2⊙Y2[n,:]+b2n)·W3[:,c] + b3[c] )
// K = 416 (13 steps; pads have a2=b2n=0 -> A=0). N = 128 = 8 frags.
// ===========================================================================
__global__ __launch_bounds__(256, 3) void gemm3_mfma(
    const unsigned short* __restrict__ Y2, const float* __restrict__ a2,
    const float* __restrict__ b2n, const unsigned short* __restrict__ W3p,
    const float* __restrict__ b3, float* __restrict__ out)
{
    const int tid = threadIdx.x;
    const int lane = tid & 63, wave = tid >> 6;
    const int quad = lane >> 4, l15 = lane & 15;
    const int n0 = blockIdx.x * 64;

    int rn[4];
#pragma unroll
    for (int mf = 0; mf < 4; mf++) rn[mf] = min(n0 + mf * 16 + l15, NN - 1);

    const s16x8* Bp = (const s16x8*)W3p;
    f32x4 acc[4][2];
#pragma unroll
    for (int mf = 0; mf < 4; mf++)
#pragma unroll
        for (int f = 0; f < 2; f++) acc[mf][f] = (f32x4){0.f, 0.f, 0.f, 0.f};

    s16x8 bcur[2], bnxt[2];
#pragma unroll
    for (int f = 0; f < 2; f++)
        bcur[f] = Bp[(size_t)(wave * 2 + f) * 64 + lane];

#pragma unroll
    for (int s = 0; s < 13; s++) {
        if (s < 12) {
#pragma unroll
            for (int f = 0; f < 2; f++)
                bnxt[f] = Bp[(size_t)((s + 1) * 8 + wave * 2 + f) * 64 + lane];
        }
        const int kb = s * 32 + quad * 8;
        float4 A0 = *(const float4*)&a2[kb],  A1 = *(const float4*)&a2[kb + 4];
        float4 B0 = *(const float4*)&b2n[kb], B1 = *(const float4*)&b2n[kb + 4];
        float Aj[8] = {A0.x, A0.y, A0.z, A0.w, A1.x, A1.y, A1.z, A1.w};
        float Bj[8] = {B0.x, B0.y, B0.z, B0.w, B1.x, B1.y, B1.z, B1.w};
#pragma unroll
        for (int mf = 0; mf < 4; mf++) {
            s16x8 yv = *(const s16x8*)&Y2[(size_t)rn[mf] * Y2S + kb];
            s16x8 af;
#pragma unroll
            for (int j = 0; j < 8; j++) {
                float y = bf2f((unsigned short)yv[j]);
                y = fmaxf(fmaf(y, Aj[j], Bj[j]), 0.f);
                af[j] = (short)f2bf(y);
            }
#pragma unroll
            for (int f = 0; f < 2; f++)
                acc[mf][f] = __builtin_amdgcn_mfma_f32_16x16x32_bf16(
                    af, bcur[f], acc[mf][f], 0, 0, 0);
        }
#pragma unroll
        for (int f = 0; f < 2; f++) bcur[f] = bnxt[f];
    }

#pragma unroll
    for (int f = 0; f < 2; f++) {
        const int col = ((wave * 2 + f) << 4) + l15;
        const float bb = b3[col];
#pragma unroll
        for (int mf = 0; mf < 4; mf++)
#pragma unroll
            for (int r = 0; r < 4; r++) {
                int n = n0 + mf * 16 + quad * 4 + r;
                if (n < NN)
                    out[(size_t)n * NF + col] = fmaxf(acc[mf][f][r] + bb, 0.f);
            }
    }
}

// ---------------------------------------------------------------------------
extern "C" void kernel_launch(void* const* d_in, const int* in_sizes, int n_in,
                              void* d_out, int out_size, void* d_ws, size_t ws_size,
                              hipStream_t stream)
{
    const float* x         = (const float*)d_in[0];
    const int*   edge_idx  = (const int*)d_in[1];
    const float* edge_attr = (const float*)d_in[2];
    // d_in[3] = u : unused by the reference
    const int*   batch     = (const int*)d_in[4];
    const float* W1        = (const float*)d_in[5];
    // d_in[6] = b1 : cancelled by BatchNorm
    const float* g1        = (const float*)d_in[7];
    const float* be1       = (const float*)d_in[8];
    const float* W2        = (const float*)d_in[9];
    // d_in[10] = b2 : cancelled by BatchNorm
    const float* g2        = (const float*)d_in[11];
    const float* be2       = (const float*)d_in[12];
    const float* W3        = (const float*)d_in[13];
    const float* b3        = (const float*)d_in[14];
    float* out = (float*)d_out;

    const int* rowE = edge_idx;        // edge_index[0]
    const int* colE = edge_idx + NE;   // edge_index[1]

    // ---- workspace layout (~97.5 MB) ----
    char* ws = (char*)d_ws;
    size_t off = 0;
    auto alloc = [&](size_t bytes) -> void* {
        void* p = ws + off;
        off += (bytes + 255) & ~(size_t)255;
        return p;
    };
    unsigned short* Y2   = (unsigned short*)alloc((size_t)NN * Y2S * 2);  // 41.6 MB
    int*            eidx = (int*)alloc((size_t)NE * 4);                   //  3.2 MB
    int*            start= (int*)alloc((size_t)(NN + 1) * 4);
    float*          a1   = (float*)alloc(LSZ * 4);
    float*          b1n  = (float*)alloc(LSZ * 4);
    unsigned short* W1p  = (unsigned short*)alloc((size_t)6  * 16 * 64 * 8 * 2); //  96 KB
    unsigned short* W2p  = (unsigned short*)alloc((size_t)12 * 26 * 64 * 8 * 2); // 312 KB
    unsigned short* W3p  = (unsigned short*)alloc((size_t)13 * 8  * 64 * 8 * 2); // 104 KB
    size_t zoff = off;                                             // ---- zero region ----
    float* agg       = (float*)alloc((size_t)NN * LSZ * 4);        // 51.2 MB
    int*   cnt       = (int*)  alloc((size_t)NN * 4);
    int*   cursor    = (int*)  alloc((size_t)NN * 4);
    float* colsum_b  = (float*)alloc(64 * LSZ * 4);
    float* colsq_b   = (float*)alloc(64 * LSZ * 4);
    float* colsum2_b = (float*)alloc(64 * Y2S * 4);                // 106 KB
    float* colsq2_b  = (float*)alloc(64 * Y2S * 4);
    float* a2        = (float*)alloc(Y2S * 4);   // pads (>=385) must stay 0
    float* b2n       = (float*)alloc(Y2S * 4);
    size_t total = off;
    if (ws_size < total) return;

    hipMemsetAsync(ws + zoff, 0, total - zoff, stream);

    // weight pre-pack into fragment order (rank-1 batch row skipped for W1/W2)
    prep_w_kernel<<<(6  * 16 * 64 + 255) / 256, 256, 0, stream>>>(W1, LSZ, LSZ, D1, 128, 16, 6,  W1p);
    prep_w_kernel<<<(12 * 26 * 64 + 255) / 256, 256, 0, stream>>>(W2, D2,  D2,  D2, 128, 26, 12, W2p);
    prep_w_kernel<<<(13 * 8  * 64 + 255) / 256, 256, 0, stream>>>(W3, NF,  NF,  D2, -1,  8,  13, W3p);

    // CSR by destination node
    hist_kernel<<<NE / 256, 256, 0, stream>>>(colE, cnt);
    scan_kernel<<<1, 1024, 0, stream>>>(cnt, start, NN);
    fill_kernel<<<NE / 256, 256, 0, stream>>>(colE, start, cursor, eidx);

    // edge MLP pass A: MFMA GEMM + fused BN stats
    gemm1_mfma<0><<<NE / 64, 256, 0, stream>>>(
        x, rowE, colE, batch, edge_attr, W1, W1p,
        nullptr, nullptr, nullptr, colsum_b, colsq_b, nullptr);
    finalize1_kernel<<<1, 256, 0, stream>>>(colsum_b, colsq_b, g1, be1, a1, b1n);

    // edge MLP pass B: recompute in CSR order, affine+relu, scatter-add
    gemm1_mfma<1><<<NE / 64, 256, 0, stream>>>(
        x, rowE, colE, batch, edge_attr, W1, W1p,
        eidx, a1, b1n, nullptr, nullptr, agg);
    divcnt_kernel<<<(NN * LSZ / 4) / 256, 256, 0, stream>>>(agg, cnt);

    // node MLP (MFMA, bf16 Y2, fused BN stats)
    gemm2_mfma<<<dim3((NN + 63) / 64, 2), 256, 0, stream>>>(
        x, batch, agg, W2, W2p, Y2, colsum2_b, colsq2_b);
    finalize2_kernel<<<2, 256, 0, stream>>>(colsum2_b, colsq2_b, g2, be2, a2, b2n);

    // output linear (MFMA, BN affine + ReLU fused into A build)
    gemm3_mfma<<<(NN + 63) / 64, 256, 0, stream>>>(Y2, a2, b2n, W3p, b3, out);
}